// Round 2
// baseline (837.631 us; speedup 1.0000x reference)
//
#include <hip/hip_runtime.h>
#include <stdint.h>
#include <stddef.h>

typedef short bf16x8 __attribute__((ext_vector_type(8)));
typedef float f32x4  __attribute__((ext_vector_type(4)));
typedef unsigned short ushort_t;

#define H_ 256
#define W_ 448
#define HP_ 258
#define WP_ 450
#define NPIX (H_*W_)
#define PPLANE (HP_*WP_)

// ---------------- workspace layout (bytes) ----------------
#define XPAD_OFF 0ull
#define XPAD_CB_STRIDE ((size_t)2*PPLANE*16)      // 3,715,200 per ci-block of 8
#define XPAD_CB_STRIDE32 (3715200u)
#define XPAD_SIZE ((size_t)64*XPAD_CB_STRIDE)     // 237,772,800
#define FPAD_OFF (XPAD_OFF + XPAD_SIZE)
#define FPAD_SIZE ((size_t)2*PPLANE*16)           // 3,715,200
#define WT_OFF   (FPAD_OFF + FPAD_SIZE)
#define WT_SIZE  ((size_t)256*9*512*2)            // 2,359,296
#define WTF_OFF  (WT_OFF + WT_SIZE)
#define WTF_SIZE ((size_t)256*128*2)              // 65,536
#define WS_NEEDED (WTF_OFF + WTF_SIZE)

__device__ __forceinline__ ushort_t bf16r(float f){
  union { float f; uint32_t u; } c; c.f = f;
  uint32_t u = c.u;
  return (ushort_t)((u + 0x7FFFu + ((u >> 16) & 1u)) >> 16);
}

// ---------------- prep: features -> padded NHWC-blocked bf16 ----------------
__global__ void prep_x(const float* __restrict__ feat, uint8_t* __restrict__ ws){
  int blk = blockIdx.x;
  int yp = blk % HP_;
  int t  = blk / HP_;
  int b  = t & 1;
  int cb = t >> 1;
  uint8_t* dst = ws + XPAD_OFF + (size_t)(cb*2 + b)*((size_t)PPLANE*16) + (size_t)yp*WP_*16;
  bool inrow = (yp >= 1 && yp <= H_);
  const float* src0 = feat + ((size_t)b*512 + (size_t)cb*8)*((size_t)H_*W_) + (size_t)(yp-1)*W_;
  for(int xp = threadIdx.x; xp < WP_; xp += blockDim.x){
    union { ushort_t u[8]; uint4 q; } v;
    if(inrow && xp >= 1 && xp <= W_){
      int x = xp - 1;
      #pragma unroll
      for(int r = 0; r < 8; r++) v.u[r] = bf16r(src0[(size_t)r*H_*W_ + x]);
    } else {
      v.q = make_uint4(0,0,0,0);
    }
    *(uint4*)(dst + (size_t)xp*16) = v.q;
  }
}

// ---------------- prep: flows -> padded NHWC bf16 (8 ch records) ----------------
__global__ void prep_f(const float* __restrict__ init_flow, const float* __restrict__ flow_fix,
                       uint8_t* __restrict__ ws){
  int blk = blockIdx.x;
  int yp = blk % HP_;
  int b  = blk / HP_;
  uint8_t* dst = ws + FPAD_OFF + ((size_t)b*PPLANE + (size_t)yp*WP_)*16;
  for(int xp = threadIdx.x; xp < WP_; xp += blockDim.x){
    union { ushort_t u[8]; uint4 q; } v;
    if(yp >= 1 && yp <= H_ && xp >= 1 && xp <= W_){
      int y = yp - 1, x = xp - 1;
      #pragma unroll
      for(int r = 0; r < 4; r++) v.u[r]   = bf16r(init_flow[(((size_t)b*4 + r)*H_ + y)*W_ + x]);
      #pragma unroll
      for(int r = 0; r < 4; r++) v.u[4+r] = bf16r(flow_fix [(((size_t)b*4 + r)*H_ + y)*W_ + x]);
    } else {
      v.q = make_uint4(0,0,0,0);
    }
    *(uint4*)(dst + (size_t)xp*16) = v.q;
  }
}

// ---------------- prep: weights -> bf16, K-contiguous layouts ----------------
__global__ void prep_w(const float* __restrict__ w1, uint8_t* __restrict__ ws){
  int idx = blockIdx.x*256 + threadIdx.x;
  ushort_t* wt  = (ushort_t*)(ws + WT_OFF);
  ushort_t* wtf = (ushort_t*)(ws + WTF_OFF);
  if(idx < 256*9*512){
    int co  = idx / (9*512);
    int rem = idx % (9*512);
    int s   = rem / 512;
    int ci  = rem % 512;
    float v = w1[((size_t)co*520 + 8 + ci)*9 + s];
    wt[((size_t)co*9 + s)*512 + ci] = bf16r(v);
  } else {
    int i2 = idx - 256*9*512;
    if(i2 < 256*128){
      int co = i2 >> 7;
      int k  = i2 & 127;
      float v = 0.f;
      if(k < 64){ int s = k >> 3, c = k & 7; v = w1[((size_t)co*520 + c)*9 + s]; }
      else if(k < 72){ int c = k - 64;       v = w1[((size_t)co*520 + c)*9 + 8]; }
      wtf[co*128 + k] = bf16r(v);
    }
  }
}

// ---------------- fused conv3x3 + PReLU + conv1x1 + softmax + merge ----------------
// BM=256 px, BN=256 co, BK=64. 8 waves (2M x 4N), wave tile 128x64.
// LDS: 2 dbuf x (A 32K + B 32K) = 128K; epilogue reuses: x-half [0,64K),
// mask f32[128][48] at 65536, W2 bf16[48][256B-swizzled rows] at 90112.
#define TILEBUF 65536
#define MASK_OFF 65536
#define W2_OFF   90112
#define SMEM_TOTAL 131072

__device__ __forceinline__ void gload16(const uint8_t* g, uint8_t* l){
  __builtin_amdgcn_global_load_lds((const __attribute__((address_space(1))) uint32_t*)g,
                                   (__attribute__((address_space(3))) uint32_t*)l, 16, 0, 0);
}
__device__ __forceinline__ void bar(){
  asm volatile("" ::: "memory");
  __builtin_amdgcn_s_barrier();
  asm volatile("" ::: "memory");
}
__device__ __forceinline__ void bar_lds(){
  asm volatile("s_waitcnt lgkmcnt(0)" ::: "memory");
  __builtin_amdgcn_s_barrier();
  asm volatile("" ::: "memory");
}

__launch_bounds__(512, 2)
__global__ void mega(const uint8_t* __restrict__ ws, const float* __restrict__ w2,
                     const float* __restrict__ b1, const float* __restrict__ pw,
                     const float* __restrict__ b2,
                     const float* __restrict__ init_flow, const float* __restrict__ flow_fix,
                     float* __restrict__ out){
  __shared__ uint8_t smem[SMEM_TOTAL];
  const int tid = threadIdx.x;
  const int l   = tid & 63;
  const int w   = tid >> 6;
  const int blk = blockIdx.x;
  const int b   = blk / 448;
  const int p0  = (blk % 448) * 256;

  // --- per-lane staging precompute (inverse-swizzled source addressing) ---
  uint32_t aoff[4], foff72[4], foff73[4], boff[4], bfl[4];
  #pragma unroll
  for(int q = 0; q < 4; q++){
    uint32_t P = (uint32_t)(q*8192 + tid*16);
    uint32_t L = P ^ (((P >> 7) & 7u) << 4);
    int m  = (int)(L >> 7);           // 0..255 pixel row
    int cb = (int)((L >> 4) & 7u);    // ci-block within row
    int p  = p0 + m;
    int y  = p / W_, x = p - y*W_;
    int pixoff = (y + 1)*WP_ + (x + 1);
    aoff[q] = (uint32_t)cb*XPAD_CB_STRIDE32 + (uint32_t)(b*(PPLANE*16)) + (uint32_t)(pixoff*16);
    int dy = cb/3, dx = cb - dy*3;
    foff72[q] = (uint32_t)((b*PPLANE + pixoff + (dy-1)*WP_ + (dx-1))*16);
    foff73[q] = (cb == 0) ? (uint32_t)((b*PPLANE + pixoff + WP_ + 1)*16) : 0u;
  }
  #pragma unroll
  for(int r = 0; r < 4; r++){
    uint32_t P = (uint32_t)(r*8192 + tid*16);
    uint32_t L = P ^ (((P >> 7) & 7u) << 4);
    uint32_t co = L >> 7, cib = L & 127u;
    boff[r] = co*9216u + cib;
    bfl[r]  = co*256u + cib;
  }

  const uint8_t* xpad = ws + XPAD_OFF;
  const uint8_t* fpad = ws + FPAD_OFF;
  const uint8_t* wt   = ws + WT_OFF;
  const uint8_t* wtf  = ws + WTF_OFF;

  // fragment-read per-lane constants
  const int wave_m = w >> 2, wave_n = w & 3;
  const uint32_t koff = ((uint32_t)(l >> 4))*16u;
  const uint32_t sw   = ((uint32_t)(l & 7)) << 4;
  const uint32_t rowA = ((uint32_t)(wave_m*128 + (l & 15)))*128u;
  const uint32_t rowB = ((uint32_t)(wave_n*64  + (l & 15)))*128u;

  const f32x4 zero4 = {0.f, 0.f, 0.f, 0.f};
  f32x4 acc[8][4];
  #pragma unroll
  for(int i = 0; i < 8; i++)
    #pragma unroll
    for(int j = 0; j < 4; j++) acc[i][j] = zero4;

  // STAGE tile tn into buffer nb (8 global_load_lds per thread: 4 A + 4 B)
  auto STAGE = [&](int tn, int nb){
    uint8_t* la = smem + nb*TILEBUF + w*1024;
    uint8_t* lb = smem + nb*TILEBUF + 32768 + w*1024;
    if(tn < 72){
      int s = tn >> 3, kk = tn & 7;
      int dy = s/3, dx = s - dy*3;
      uint32_t stepA = (uint32_t)(kk*8)*XPAD_CB_STRIDE32 + (uint32_t)(((dy-1)*WP_ + (dx-1))*16);
      uint32_t stepB = (uint32_t)(s*1024 + kk*128);
      #pragma unroll
      for(int q = 0; q < 4; q++) gload16(xpad + (aoff[q] + stepA), la + q*8192);
      #pragma unroll
      for(int r = 0; r < 4; r++) gload16(wt + (boff[r] + stepB), lb + r*8192);
    } else if(tn == 72){   // flow taps 0..7
      #pragma unroll
      for(int q = 0; q < 4; q++) gload16(fpad + foff72[q], la + q*8192);
      #pragma unroll
      for(int r = 0; r < 4; r++) gload16(wtf + bfl[r], lb + r*8192);
    } else {               // flow tap 8 (+ zeros)
      #pragma unroll
      for(int q = 0; q < 4; q++) gload16(fpad + foff73[q], la + q*8192);
      #pragma unroll
      for(int r = 0; r < 4; r++) gload16(wtf + (bfl[r] + 128u), lb + r*8192);
    }
  };

  auto COMPUTE = [&](const uint8_t* A){
    const uint8_t* Bp = A + 32768;
    __builtin_amdgcn_s_setprio(1);
    #pragma unroll
    for(int kc = 0; kc < 2; kc++){
      bf16x8 av[8];
      #pragma unroll
      for(int mi = 0; mi < 8; mi++)
        av[mi] = *(const bf16x8*)(A + ((rowA + (uint32_t)(mi*2048 + kc*64) + koff) ^ sw));
      #pragma unroll
      for(int ni = 0; ni < 4; ni++){
        bf16x8 bv = *(const bf16x8*)(Bp + ((rowB + (uint32_t)(ni*2048 + kc*64) + koff) ^ sw));
        #pragma unroll
        for(int mi = 0; mi < 8; mi++)
          acc[mi][ni] = __builtin_amdgcn_mfma_f32_16x16x32_bf16(av[mi], bv, acc[mi][ni], 0, 0, 0);
      }
    }
    __builtin_amdgcn_s_setprio(0);
  };

  // prologue: stage tile 0 into buf 0
  STAGE(0, 0);

  // main loop t = 0..71 (steady state, counted vmcnt, no drains)
  #pragma unroll 2
  for(int t = 0; t < 72; t++){
    STAGE(t + 1, (t + 1) & 1);
    asm volatile("s_waitcnt vmcnt(8)" ::: "memory");  // tile t landed; t+1 in flight
    __builtin_amdgcn_s_barrier();
    asm volatile("" ::: "memory");
    COMPUTE(smem + (t & 1)*TILEBUF);
    bar();
  }
  // t = 72: stage 73, compute 72
  STAGE(73, 1);
  asm volatile("s_waitcnt vmcnt(8)" ::: "memory");
  __builtin_amdgcn_s_barrier();
  asm volatile("" ::: "memory");
  COMPUTE(smem + 0*TILEBUF);
  bar();
  // t = 73: compute 73 (drain all)
  asm volatile("s_waitcnt vmcnt(0)" ::: "memory");
  __builtin_amdgcn_s_barrier();
  asm volatile("" ::: "memory");
  COMPUTE(smem + 1*TILEBUF);
  bar();

  // --- stage W2 (fp32 -> bf16) into LDS, rows of 512B, XOR-swizzled ---
  for(int e = tid; e < 48*256; e += 512){
    int row = e >> 8, k = e & 255;
    float f = (row < 36) ? w2[row*256 + k] : 0.f;
    uint32_t phys = ((uint32_t)(row*512 + k*2)) ^ (((uint32_t)(row & 7)) << 4);
    *(ushort_t*)(smem + W2_OFF + phys) = bf16r(f);
  }

  // --- epilogue: two passes of 128 pixels each ---
  #pragma unroll
  for(int pass = 0; pass < 2; pass++){
    if(pass) bar();   // pass-0 softmax/merge done before overwriting x-half & mask
    if(wave_m == pass){
      #pragma unroll
      for(int ni = 0; ni < 4; ni++){
        int co = wave_n*64 + ni*16 + (l & 15);
        float bb = b1[co];
        float pp = pw[co];
        #pragma unroll
        for(int mi = 0; mi < 8; mi++){
          #pragma unroll
          for(int j = 0; j < 4; j++){
            float v = acc[mi][ni][j] + bb;
            v = (v < 0.f) ? v*pp : v;
            int px = mi*16 + ((l >> 4) << 2) + j;     // 0..127 within the pass
            uint32_t phys = ((uint32_t)(px*512 + co*2)) ^ (((uint32_t)(px & 7)) << 4);
            *(ushort_t*)(smem + phys) = bf16r(v);
          }
        }
      }
    }
    bar_lds();   // x-half (and W2 on pass 0) visible to all

    // mask GEMM: wave w -> pixel rows [16w, 16w+16), N=48 (36 valid), K=256
    f32x4 acc2[3];
    #pragma unroll
    for(int ni = 0; ni < 3; ni++) acc2[ni] = zero4;
    {
      const uint32_t rowX = ((uint32_t)(16*w + (l & 15)))*512u;
      #pragma unroll
      for(int kk = 0; kk < 8; kk++){
        bf16x8 av = *(const bf16x8*)(smem + ((rowX + (uint32_t)(kk*64) + koff) ^ sw));
        #pragma unroll
        for(int ni = 0; ni < 3; ni++){
          uint32_t rowW = ((uint32_t)(ni*16 + (l & 15)))*512u;
          bf16x8 bv = *(const bf16x8*)(smem + W2_OFF + ((rowW + (uint32_t)(kk*64) + koff) ^ sw));
          acc2[ni] = __builtin_amdgcn_mfma_f32_16x16x32_bf16(av, bv, acc2[ni], 0, 0, 0);
        }
      }
    }
    {
      float* ml = (float*)(smem + MASK_OFF);
      #pragma unroll
      for(int ni = 0; ni < 3; ni++){
        int co2 = ni*16 + (l & 15);
        float bb2 = b2[co2 < 36 ? co2 : 35];
        #pragma unroll
        for(int j = 0; j < 4; j++){
          int px = 16*w + ((l >> 4) << 2) + j;
          ml[px*48 + co2] = acc2[ni][j] + bb2;
        }
      }
    }
    bar_lds();

    // softmax(2x18) + unfold-merge, 4 threads per pixel (128 px per pass)
    {
      int px = tid >> 2;
      int hh = (tid >> 1) & 1;
      int c  = tid & 1;
      const float* ml = (const float*)(smem + MASK_OFF) + px*48 + hh*18;
      float mx = ml[0];
      #pragma unroll
      for(int k = 1; k < 18; k++) mx = fmaxf(mx, ml[k]);
      float e[18]; float sum = 0.f;
      #pragma unroll
      for(int k = 0; k < 18; k++){ e[k] = __expf(ml[k] - mx); sum += e[k]; }
      float inv = 1.f / sum;
      int p = p0 + pass*128 + px;
      int y = p / W_, x = p - y*W_;
      const float* fi = init_flow + (size_t)(b*4 + 2*hh + c)*NPIX;
      const float* ff = flow_fix  + (size_t)(b*4 + 2*hh + c)*NPIX;
      float o = 0.f;
      #pragma unroll
      for(int s = 0; s < 9; s++){
        int yy = y + (s/3) - 1, xx = x + (s%3) - 1;
        if(yy >= 0 && yy < H_ && xx >= 0 && xx < W_){
          int idx = yy*W_ + xx;
          o += e[s]*fi[idx] + e[9+s]*ff[idx];
        }
      }
      out[(size_t)((b + 2*hh)*2 + c)*NPIX + y*W_ + x] = o * inv;
    }
  }
}

// ---------------- launcher ----------------
extern "C" void kernel_launch(void* const* d_in, const int* in_sizes, int n_in,
                              void* d_out, int out_size, void* d_ws, size_t ws_size,
                              hipStream_t stream) {
  const float* feature   = (const float*)d_in[0];
  const float* init_flow = (const float*)d_in[1];
  const float* flow_fix  = (const float*)d_in[2];
  const float* w1        = (const float*)d_in[3];
  const float* b1        = (const float*)d_in[4];
  const float* prelu_w   = (const float*)d_in[5];
  const float* w2        = (const float*)d_in[6];
  const float* b2        = (const float*)d_in[7];
  float* out = (float*)d_out;
  uint8_t* ws = (uint8_t*)d_ws;

  if(ws_size < WS_NEEDED) return;  // insufficient workspace -> fail visibly

  prep_x<<<64*2*HP_, 256, 0, stream>>>(feature, ws);
  prep_f<<<2*HP_,    256, 0, stream>>>(init_flow, flow_fix, ws);
  prep_w<<<4736,     256, 0, stream>>>(w1, ws);
  mega<<<896, 512, 0, stream>>>(ws, w2, b1, prelu_w, b2, init_flow, flow_fix, out);
}

// Round 3
// 786.079 us; speedup vs baseline: 1.0656x; 1.0656x over previous
//
#include <hip/hip_runtime.h>
#include <stdint.h>
#include <stddef.h>

typedef short bf16x8 __attribute__((ext_vector_type(8)));
typedef float f32x4  __attribute__((ext_vector_type(4)));
typedef unsigned short ushort_t;

#define H_ 256
#define W_ 448
#define HP_ 258
#define WP_ 450
#define NPIX (H_*W_)
#define PPLANE (HP_*WP_)

// ---------------- workspace layout (bytes) ----------------
#define XPAD_OFF 0ull
#define XPAD_CB_STRIDE ((size_t)2*PPLANE*16)      // 3,715,200 per ci-block of 8
#define XPAD_CB_STRIDE32 (3715200u)
#define XPAD_SIZE ((size_t)64*XPAD_CB_STRIDE)     // 237,772,800
#define FPAD_OFF (XPAD_OFF + XPAD_SIZE)
#define FPAD_SIZE ((size_t)2*PPLANE*16)           // 3,715,200
#define WT_OFF   (FPAD_OFF + FPAD_SIZE)
#define WT_SIZE  ((size_t)256*9*512*2)            // 2,359,296
#define WTF_OFF  (WT_OFF + WT_SIZE)
#define WTF_SIZE ((size_t)256*128*2)              // 65,536
#define WS_NEEDED (WTF_OFF + WTF_SIZE)

__device__ __forceinline__ ushort_t bf16r(float f){
  union { float f; uint32_t u; } c; c.f = f;
  uint32_t u = c.u;
  return (ushort_t)((u + 0x7FFFu + ((u >> 16) & 1u)) >> 16);
}

// ---------------- prep: features -> padded NHWC-blocked bf16 ----------------
__global__ void prep_x(const float* __restrict__ feat, uint8_t* __restrict__ ws){
  int blk = blockIdx.x;
  int yp = blk % HP_;
  int t  = blk / HP_;
  int b  = t & 1;
  int cb = t >> 1;
  uint8_t* dst = ws + XPAD_OFF + (size_t)(cb*2 + b)*((size_t)PPLANE*16) + (size_t)yp*WP_*16;
  bool inrow = (yp >= 1 && yp <= H_);
  const float* src0 = feat + ((size_t)b*512 + (size_t)cb*8)*((size_t)H_*W_) + (size_t)(yp-1)*W_;
  for(int xp = threadIdx.x; xp < WP_; xp += blockDim.x){
    union { ushort_t u[8]; uint4 q; } v;
    if(inrow && xp >= 1 && xp <= W_){
      int x = xp - 1;
      #pragma unroll
      for(int r = 0; r < 8; r++) v.u[r] = bf16r(src0[(size_t)r*H_*W_ + x]);
    } else {
      v.q = make_uint4(0,0,0,0);
    }
    *(uint4*)(dst + (size_t)xp*16) = v.q;
  }
}

// ---------------- prep: flows -> padded NHWC bf16 (8 ch records) ----------------
__global__ void prep_f(const float* __restrict__ init_flow, const float* __restrict__ flow_fix,
                       uint8_t* __restrict__ ws){
  int blk = blockIdx.x;
  int yp = blk % HP_;
  int b  = blk / HP_;
  uint8_t* dst = ws + FPAD_OFF + ((size_t)b*PPLANE + (size_t)yp*WP_)*16;
  for(int xp = threadIdx.x; xp < WP_; xp += blockDim.x){
    union { ushort_t u[8]; uint4 q; } v;
    if(yp >= 1 && yp <= H_ && xp >= 1 && xp <= W_){
      int y = yp - 1, x = xp - 1;
      #pragma unroll
      for(int r = 0; r < 4; r++) v.u[r]   = bf16r(init_flow[(((size_t)b*4 + r)*H_ + y)*W_ + x]);
      #pragma unroll
      for(int r = 0; r < 4; r++) v.u[4+r] = bf16r(flow_fix [(((size_t)b*4 + r)*H_ + y)*W_ + x]);
    } else {
      v.q = make_uint4(0,0,0,0);
    }
    *(uint4*)(dst + (size_t)xp*16) = v.q;
  }
}

// ---------------- prep: weights -> bf16, K-contiguous layouts ----------------
__global__ void prep_w(const float* __restrict__ w1, uint8_t* __restrict__ ws){
  int idx = blockIdx.x*256 + threadIdx.x;
  ushort_t* wt  = (ushort_t*)(ws + WT_OFF);
  ushort_t* wtf = (ushort_t*)(ws + WTF_OFF);
  if(idx < 256*9*512){
    int co  = idx / (9*512);
    int rem = idx % (9*512);
    int s   = rem / 512;
    int ci  = rem % 512;
    float v = w1[((size_t)co*520 + 8 + ci)*9 + s];
    wt[((size_t)co*9 + s)*512 + ci] = bf16r(v);
  } else {
    int i2 = idx - 256*9*512;
    if(i2 < 256*128){
      int co = i2 >> 7;
      int k  = i2 & 127;
      float v = 0.f;
      if(k < 64){ int s = k >> 3, c = k & 7; v = w1[((size_t)co*520 + c)*9 + s]; }
      else if(k < 72){ int c = k - 64;       v = w1[((size_t)co*520 + c)*9 + 8]; }
      wtf[co*128 + k] = bf16r(v);
    }
  }
}

// ---------------- fused conv3x3 + PReLU + conv1x1 + softmax + merge ----------------
// BM=256 px, BN=256 co, BK=64. 8 waves (2M x 4N), wave tile 128x64.
// 4-phase-per-K-tile schedule (m201-style): each phase = {ds_read frags ||
// stage-issue} -> bar -> lgkmcnt(0) -> setprio(1) 16xMFMA setprio(0) -> bar.
// LDS: 2 dbuf x (A 32K + B 32K) = 128K; epilogue reuses buffers.
#define TILEBUF 65536
#define MASK_OFF 65536
#define W2_OFF   90112
#define SMEM_TOTAL 131072

__device__ __forceinline__ void gload16(const uint8_t* g, uint8_t* l){
  __builtin_amdgcn_global_load_lds((const __attribute__((address_space(1))) uint32_t*)g,
                                   (__attribute__((address_space(3))) uint32_t*)l, 16, 0, 0);
}
__device__ __forceinline__ void bar(){
  asm volatile("" ::: "memory");
  __builtin_amdgcn_s_barrier();
  asm volatile("" ::: "memory");
}
__device__ __forceinline__ void bar_lds(){
  asm volatile("s_waitcnt lgkmcnt(0)" ::: "memory");
  __builtin_amdgcn_s_barrier();
  asm volatile("" ::: "memory");
}
__device__ __forceinline__ void lgkm0(){
  asm volatile("s_waitcnt lgkmcnt(0)" ::: "memory");
}

__launch_bounds__(512, 2)
__global__ void mega(const uint8_t* __restrict__ ws, const float* __restrict__ w2,
                     const float* __restrict__ b1, const float* __restrict__ pw,
                     const float* __restrict__ b2,
                     const float* __restrict__ init_flow, const float* __restrict__ flow_fix,
                     float* __restrict__ out){
  __shared__ uint8_t smem[SMEM_TOTAL];
  const int tid = threadIdx.x;
  const int l   = tid & 63;
  const int w   = tid >> 6;
  // T1: XCD-aware bijective swizzle (896 = 8 * 112)
  const int blk0 = blockIdx.x;
  const int blk  = (blk0 & 7)*112 + (blk0 >> 3);
  const int b   = blk / 448;
  const int p0  = (blk % 448) * 256;

  // --- per-lane staging precompute (inverse-swizzled source addressing) ---
  uint32_t aoff[4], foff72[4], foff73[4], boff[4], bfl[4];
  #pragma unroll
  for(int q = 0; q < 4; q++){
    uint32_t P = (uint32_t)(q*8192 + tid*16);
    uint32_t L = P ^ (((P >> 7) & 7u) << 4);
    int m  = (int)(L >> 7);           // 0..255 pixel row
    int cb = (int)((L >> 4) & 7u);    // ci-block within row
    int p  = p0 + m;
    int y  = p / W_, x = p - y*W_;
    int pixoff = (y + 1)*WP_ + (x + 1);
    aoff[q] = (uint32_t)cb*XPAD_CB_STRIDE32 + (uint32_t)(b*(PPLANE*16)) + (uint32_t)(pixoff*16);
    int dy = cb/3, dx = cb - dy*3;
    foff72[q] = (uint32_t)((b*PPLANE + pixoff + (dy-1)*WP_ + (dx-1))*16);
    foff73[q] = (cb == 0) ? (uint32_t)((b*PPLANE + pixoff + WP_ + 1)*16) : 0u;
  }
  #pragma unroll
  for(int r = 0; r < 4; r++){
    uint32_t P = (uint32_t)(r*8192 + tid*16);
    uint32_t L = P ^ (((P >> 7) & 7u) << 4);
    uint32_t co = L >> 7, cib = L & 127u;
    boff[r] = co*9216u + cib;
    bfl[r]  = co*256u + cib;
  }

  const uint8_t* xpad = ws + XPAD_OFF;
  const uint8_t* fpad = ws + FPAD_OFF;
  const uint8_t* wt   = ws + WT_OFF;
  const uint8_t* wtf  = ws + WTF_OFF;

  // fragment-read per-lane constants
  const int wave_m = w >> 2, wave_n = w & 3;
  const uint32_t koff = ((uint32_t)(l >> 4))*16u;
  const uint32_t sw   = ((uint32_t)(l & 7)) << 4;
  const uint32_t rowA = ((uint32_t)(wave_m*128 + (l & 15)))*128u;
  const uint32_t rowB = ((uint32_t)(wave_n*64  + (l & 15)))*128u;

  const f32x4 zero4 = {0.f, 0.f, 0.f, 0.f};
  f32x4 acc[8][4];
  #pragma unroll
  for(int i = 0; i < 8; i++)
    #pragma unroll
    for(int j = 0; j < 4; j++) acc[i][j] = zero4;

  // staging halves: A (4 gload) and B (4 gload) of tile tn into buffer nb
  auto STAGE_A = [&](int tn, int nb){
    uint8_t* la = smem + nb*TILEBUF + w*1024;
    if(tn < 72){
      int s = tn >> 3, kk = tn & 7;
      int dy = s/3, dx = s - dy*3;
      uint32_t stepA = (uint32_t)(kk*8)*XPAD_CB_STRIDE32 + (uint32_t)(((dy-1)*WP_ + (dx-1))*16);
      #pragma unroll
      for(int q = 0; q < 4; q++) gload16(xpad + (aoff[q] + stepA), la + q*8192);
    } else if(tn == 72){
      #pragma unroll
      for(int q = 0; q < 4; q++) gload16(fpad + foff72[q], la + q*8192);
    } else {
      #pragma unroll
      for(int q = 0; q < 4; q++) gload16(fpad + foff73[q], la + q*8192);
    }
  };
  auto STAGE_B = [&](int tn, int nb){
    uint8_t* lb = smem + nb*TILEBUF + 32768 + w*1024;
    if(tn < 72){
      int s = tn >> 3, kk = tn & 7;
      uint32_t stepB = (uint32_t)(s*1024 + kk*128);
      #pragma unroll
      for(int r = 0; r < 4; r++) gload16(wt + (boff[r] + stepB), lb + r*8192);
    } else if(tn == 72){
      #pragma unroll
      for(int r = 0; r < 4; r++) gload16(wtf + bfl[r], lb + r*8192);
    } else {
      #pragma unroll
      for(int r = 0; r < 4; r++) gload16(wtf + (bfl[r] + 128u), lb + r*8192);
    }
  };

  // prologue: stage tile 0 into buf 0, drain, barrier
  STAGE_A(0, 0);
  STAGE_B(0, 0);
  asm volatile("s_waitcnt vmcnt(0)" ::: "memory");
  bar();

  for(int t = 0; t < 74; t++){
    const uint8_t* A  = smem + (t & 1)*TILEBUF;
    const uint8_t* Bp = A + 32768;
    const int nb = (t & 1) ^ 1;
    const int tn = t + 1;
    bf16x8 av[8], bv0, bv1;

    // ---- phase 0: kc=0 A+B(n0,n1) reads; issue A(t+1) staging ----
    #pragma unroll
    for(int mi = 0; mi < 8; mi++)
      av[mi] = *(const bf16x8*)(A + ((rowA + (uint32_t)(mi*2048) + koff) ^ sw));
    bv0 = *(const bf16x8*)(Bp + ((rowB + 0u    + koff) ^ sw));
    bv1 = *(const bf16x8*)(Bp + ((rowB + 2048u + koff) ^ sw));
    if(tn < 74) STAGE_A(tn, nb);
    bar();
    lgkm0();
    __builtin_amdgcn_s_setprio(1);
    #pragma unroll
    for(int mi = 0; mi < 8; mi++)
      acc[mi][0] = __builtin_amdgcn_mfma_f32_16x16x32_bf16(av[mi], bv0, acc[mi][0], 0, 0, 0);
    #pragma unroll
    for(int mi = 0; mi < 8; mi++)
      acc[mi][1] = __builtin_amdgcn_mfma_f32_16x16x32_bf16(av[mi], bv1, acc[mi][1], 0, 0, 0);
    __builtin_amdgcn_s_setprio(0);
    bar();

    // ---- phase 1: kc=0 B(n2,n3) reads; issue B(t+1) staging ----
    bv0 = *(const bf16x8*)(Bp + ((rowB + 4096u + koff) ^ sw));
    bv1 = *(const bf16x8*)(Bp + ((rowB + 6144u + koff) ^ sw));
    if(tn < 74) STAGE_B(tn, nb);
    bar();
    lgkm0();
    __builtin_amdgcn_s_setprio(1);
    #pragma unroll
    for(int mi = 0; mi < 8; mi++)
      acc[mi][2] = __builtin_amdgcn_mfma_f32_16x16x32_bf16(av[mi], bv0, acc[mi][2], 0, 0, 0);
    #pragma unroll
    for(int mi = 0; mi < 8; mi++)
      acc[mi][3] = __builtin_amdgcn_mfma_f32_16x16x32_bf16(av[mi], bv1, acc[mi][3], 0, 0, 0);
    __builtin_amdgcn_s_setprio(0);
    bar();

    // ---- phase 2: kc=1 A+B(n0,n1) reads ----
    #pragma unroll
    for(int mi = 0; mi < 8; mi++)
      av[mi] = *(const bf16x8*)(A + ((rowA + (uint32_t)(mi*2048) + 64u + koff) ^ sw));
    bv0 = *(const bf16x8*)(Bp + ((rowB + 64u   + koff) ^ sw));
    bv1 = *(const bf16x8*)(Bp + ((rowB + 2112u + koff) ^ sw));
    bar();
    lgkm0();
    __builtin_amdgcn_s_setprio(1);
    #pragma unroll
    for(int mi = 0; mi < 8; mi++)
      acc[mi][0] = __builtin_amdgcn_mfma_f32_16x16x32_bf16(av[mi], bv0, acc[mi][0], 0, 0, 0);
    #pragma unroll
    for(int mi = 0; mi < 8; mi++)
      acc[mi][1] = __builtin_amdgcn_mfma_f32_16x16x32_bf16(av[mi], bv1, acc[mi][1], 0, 0, 0);
    __builtin_amdgcn_s_setprio(0);
    bar();

    // ---- phase 3: kc=1 B(n2,n3) reads; vmcnt(0) retires tile t+1 (issued ~3 phases ago) ----
    bv0 = *(const bf16x8*)(Bp + ((rowB + 4160u + koff) ^ sw));
    bv1 = *(const bf16x8*)(Bp + ((rowB + 6208u + koff) ^ sw));
    bar();
    lgkm0();
    __builtin_amdgcn_s_setprio(1);
    #pragma unroll
    for(int mi = 0; mi < 8; mi++)
      acc[mi][2] = __builtin_amdgcn_mfma_f32_16x16x32_bf16(av[mi], bv0, acc[mi][2], 0, 0, 0);
    #pragma unroll
    for(int mi = 0; mi < 8; mi++)
      acc[mi][3] = __builtin_amdgcn_mfma_f32_16x16x32_bf16(av[mi], bv1, acc[mi][3], 0, 0, 0);
    __builtin_amdgcn_s_setprio(0);
    asm volatile("s_waitcnt vmcnt(0)" ::: "memory");
    bar();
  }

  // --- stage W2 (fp32 -> bf16) into LDS, rows of 512B, XOR-swizzled ---
  for(int e = tid; e < 48*256; e += 512){
    int row = e >> 8, k = e & 255;
    float f = (row < 36) ? w2[row*256 + k] : 0.f;
    uint32_t phys = ((uint32_t)(row*512 + k*2)) ^ (((uint32_t)(row & 7)) << 4);
    *(ushort_t*)(smem + W2_OFF + phys) = bf16r(f);
  }

  // --- epilogue: two passes of 128 pixels each ---
  #pragma unroll
  for(int pass = 0; pass < 2; pass++){
    if(pass) bar();   // pass-0 softmax/merge done before overwriting x-half & mask
    if(wave_m == pass){
      #pragma unroll
      for(int ni = 0; ni < 4; ni++){
        int co = wave_n*64 + ni*16 + (l & 15);
        float bb = b1[co];
        float pp = pw[co];
        #pragma unroll
        for(int mi = 0; mi < 8; mi++){
          #pragma unroll
          for(int j = 0; j < 4; j++){
            float v = acc[mi][ni][j] + bb;
            v = (v < 0.f) ? v*pp : v;
            int px = mi*16 + ((l >> 4) << 2) + j;     // 0..127 within the pass
            uint32_t phys = ((uint32_t)(px*512 + co*2)) ^ (((uint32_t)(px & 7)) << 4);
            *(ushort_t*)(smem + phys) = bf16r(v);
          }
        }
      }
    }
    bar_lds();   // x-half (and W2 on pass 0) visible to all

    // mask GEMM: wave w -> pixel rows [16w, 16w+16), N=48 (36 valid), K=256
    f32x4 acc2[3];
    #pragma unroll
    for(int ni = 0; ni < 3; ni++) acc2[ni] = zero4;
    {
      const uint32_t rowX = ((uint32_t)(16*w + (l & 15)))*512u;
      #pragma unroll
      for(int kk = 0; kk < 8; kk++){
        bf16x8 av = *(const bf16x8*)(smem + ((rowX + (uint32_t)(kk*64) + koff) ^ sw));
        #pragma unroll
        for(int ni = 0; ni < 3; ni++){
          uint32_t rowW = ((uint32_t)(ni*16 + (l & 15)))*512u;
          bf16x8 bv = *(const bf16x8*)(smem + W2_OFF + ((rowW + (uint32_t)(kk*64) + koff) ^ sw));
          acc2[ni] = __builtin_amdgcn_mfma_f32_16x16x32_bf16(av, bv, acc2[ni], 0, 0, 0);
        }
      }
    }
    {
      float* ml = (float*)(smem + MASK_OFF);
      #pragma unroll
      for(int ni = 0; ni < 3; ni++){
        int co2 = ni*16 + (l & 15);
        float bb2 = b2[co2 < 36 ? co2 : 35];
        #pragma unroll
        for(int j = 0; j < 4; j++){
          int px = 16*w + ((l >> 4) << 2) + j;
          ml[px*48 + co2] = acc2[ni][j] + bb2;
        }
      }
    }
    bar_lds();

    // softmax(2x18) + unfold-merge, 4 threads per pixel (128 px per pass)
    {
      int px = tid >> 2;
      int hh = (tid >> 1) & 1;
      int c  = tid & 1;
      const float* ml = (const float*)(smem + MASK_OFF) + px*48 + hh*18;
      float mx = ml[0];
      #pragma unroll
      for(int k = 1; k < 18; k++) mx = fmaxf(mx, ml[k]);
      float e[18]; float sum = 0.f;
      #pragma unroll
      for(int k = 0; k < 18; k++){ e[k] = __expf(ml[k] - mx); sum += e[k]; }
      float inv = 1.f / sum;
      int p = p0 + pass*128 + px;
      int y = p / W_, x = p - y*W_;
      const float* fi = init_flow + (size_t)(b*4 + 2*hh + c)*NPIX;
      const float* ff = flow_fix  + (size_t)(b*4 + 2*hh + c)*NPIX;
      float o = 0.f;
      #pragma unroll
      for(int s = 0; s < 9; s++){
        int yy = y + (s/3) - 1, xx = x + (s%3) - 1;
        if(yy >= 0 && yy < H_ && xx >= 0 && xx < W_){
          int idx = yy*W_ + xx;
          o += e[s]*fi[idx] + e[9+s]*ff[idx];
        }
      }
      out[(size_t)((b + 2*hh)*2 + c)*NPIX + y*W_ + x] = o * inv;
    }
  }
}

// ---------------- launcher ----------------
extern "C" void kernel_launch(void* const* d_in, const int* in_sizes, int n_in,
                              void* d_out, int out_size, void* d_ws, size_t ws_size,
                              hipStream_t stream) {
  const float* feature   = (const float*)d_in[0];
  const float* init_flow = (const float*)d_in[1];
  const float* flow_fix  = (const float*)d_in[2];
  const float* w1        = (const float*)d_in[3];
  const float* b1        = (const float*)d_in[4];
  const float* prelu_w   = (const float*)d_in[5];
  const float* w2        = (const float*)d_in[6];
  const float* b2        = (const float*)d_in[7];
  float* out = (float*)d_out;
  uint8_t* ws = (uint8_t*)d_ws;

  if(ws_size < WS_NEEDED) return;  // insufficient workspace -> fail visibly

  prep_x<<<64*2*HP_, 256, 0, stream>>>(feature, ws);
  prep_f<<<2*HP_,    256, 0, stream>>>(init_flow, flow_fix, ws);
  prep_w<<<4736,     256, 0, stream>>>(w1, ws);
  mega<<<896, 512, 0, stream>>>(ws, w2, b1, prelu_w, b2, init_flow, flow_fix, out);
}

// Round 4
// 774.175 us; speedup vs baseline: 1.0820x; 1.0154x over previous
//
#include <hip/hip_runtime.h>
#include <stdint.h>
#include <stddef.h>

typedef short bf16x8 __attribute__((ext_vector_type(8)));
typedef float f32x4  __attribute__((ext_vector_type(4)));
typedef unsigned short ushort_t;

#define H_ 256
#define W_ 448
#define HP_ 258
#define WP_ 450
#define NPIX (H_*W_)
#define PPLANE (HP_*WP_)

// ---------------- workspace layout (bytes) ----------------
#define XPAD_OFF 0ull
#define XPAD_CB_STRIDE ((size_t)2*PPLANE*16)      // 3,715,200 per ci-block of 8
#define XPAD_CB_STRIDE32 (3715200u)
#define XPAD_SIZE ((size_t)64*XPAD_CB_STRIDE)     // 237,772,800
#define FPAD_OFF (XPAD_OFF + XPAD_SIZE)
#define FPAD_SIZE ((size_t)2*PPLANE*16)           // 3,715,200
#define WT_OFF   (FPAD_OFF + FPAD_SIZE)
#define WT_SIZE  ((size_t)256*9*512*2)            // 2,359,296
#define WTF_OFF  (WT_OFF + WT_SIZE)
#define WTF_SIZE ((size_t)256*128*2)              // 65,536
#define WS_NEEDED (WTF_OFF + WTF_SIZE)

__device__ __forceinline__ ushort_t bf16r(float f){
  union { float f; uint32_t u; } c; c.f = f;
  uint32_t u = c.u;
  return (ushort_t)((u + 0x7FFFu + ((u >> 16) & 1u)) >> 16);
}

// ---------------- prep: features -> padded NHWC-blocked bf16 ----------------
__global__ void prep_x(const float* __restrict__ feat, uint8_t* __restrict__ ws){
  int blk = blockIdx.x;
  int yp = blk % HP_;
  int t  = blk / HP_;
  int b  = t & 1;
  int cb = t >> 1;
  uint8_t* dst = ws + XPAD_OFF + (size_t)(cb*2 + b)*((size_t)PPLANE*16) + (size_t)yp*WP_*16;
  bool inrow = (yp >= 1 && yp <= H_);
  const float* src0 = feat + ((size_t)b*512 + (size_t)cb*8)*((size_t)H_*W_) + (size_t)(yp-1)*W_;
  for(int xp = threadIdx.x; xp < WP_; xp += blockDim.x){
    union { ushort_t u[8]; uint4 q; } v;
    if(inrow && xp >= 1 && xp <= W_){
      int x = xp - 1;
      #pragma unroll
      for(int r = 0; r < 8; r++) v.u[r] = bf16r(src0[(size_t)r*H_*W_ + x]);
    } else {
      v.q = make_uint4(0,0,0,0);
    }
    *(uint4*)(dst + (size_t)xp*16) = v.q;
  }
}

// ---------------- prep: flows -> padded NHWC bf16 (8 ch records) ----------------
__global__ void prep_f(const float* __restrict__ init_flow, const float* __restrict__ flow_fix,
                       uint8_t* __restrict__ ws){
  int blk = blockIdx.x;
  int yp = blk % HP_;
  int b  = blk / HP_;
  uint8_t* dst = ws + FPAD_OFF + ((size_t)b*PPLANE + (size_t)yp*WP_)*16;
  for(int xp = threadIdx.x; xp < WP_; xp += blockDim.x){
    union { ushort_t u[8]; uint4 q; } v;
    if(yp >= 1 && yp <= H_ && xp >= 1 && xp <= W_){
      int y = yp - 1, x = xp - 1;
      #pragma unroll
      for(int r = 0; r < 4; r++) v.u[r]   = bf16r(init_flow[(((size_t)b*4 + r)*H_ + y)*W_ + x]);
      #pragma unroll
      for(int r = 0; r < 4; r++) v.u[4+r] = bf16r(flow_fix [(((size_t)b*4 + r)*H_ + y)*W_ + x]);
    } else {
      v.q = make_uint4(0,0,0,0);
    }
    *(uint4*)(dst + (size_t)xp*16) = v.q;
  }
}

// ---------------- prep: weights -> bf16, K-contiguous layouts ----------------
__global__ void prep_w(const float* __restrict__ w1, uint8_t* __restrict__ ws){
  int idx = blockIdx.x*256 + threadIdx.x;
  ushort_t* wt  = (ushort_t*)(ws + WT_OFF);
  ushort_t* wtf = (ushort_t*)(ws + WTF_OFF);
  if(idx < 256*9*512){
    int co  = idx / (9*512);
    int rem = idx % (9*512);
    int s   = rem / 512;
    int ci  = rem % 512;
    float v = w1[((size_t)co*520 + 8 + ci)*9 + s];
    wt[((size_t)co*9 + s)*512 + ci] = bf16r(v);
  } else {
    int i2 = idx - 256*9*512;
    if(i2 < 256*128){
      int co = i2 >> 7;
      int k  = i2 & 127;
      float v = 0.f;
      if(k < 64){ int s = k >> 3, c = k & 7; v = w1[((size_t)co*520 + c)*9 + s]; }
      else if(k < 72){ int c = k - 64;       v = w1[((size_t)co*520 + c)*9 + 8]; }
      wtf[co*128 + k] = bf16r(v);
    }
  }
}

// ---------------- fused conv3x3 + PReLU + conv1x1 + softmax + merge ----------------
// BM=256 px, BN=256 co, BK=64. 8 waves (2M x 4N), wave tile 128x64.
// 4-phase schedule with STAGGERED counted vmcnt (m201/m218 discipline):
//   ph0=(A-rows 0-63, kc0): read av[0..3]kc0 + bv0[4]; issue A02(t+1)+B(t+1)
//   ph1=(rows 0-63, kc1):   read av kc1 + bv1[4];      end: vmcnt(6) retires A13(t)
//   ph2=(rows 64-127, kc0): read av kc0 (bv0 in regs); issue A13(t+1)
//   ph3=(rows 64-127, kc1): read av kc1 (bv1 in regs); end: vmcnt(2) retires A02+B(t+1)
// vmcnt never 0 in steady state. LDS: 2 dbuf x 64K; epilogue reuses buffers.
#define TILEBUF 65536
#define MASK_OFF 65536
#define W2_OFF   90112
#define SMEM_TOTAL 131072

__device__ __forceinline__ void gload16(const uint8_t* g, uint8_t* l){
  __builtin_amdgcn_global_load_lds((const __attribute__((address_space(1))) uint32_t*)g,
                                   (__attribute__((address_space(3))) uint32_t*)l, 16, 0, 0);
}
__device__ __forceinline__ void bar(){
  asm volatile("" ::: "memory");
  __builtin_amdgcn_s_barrier();
  asm volatile("" ::: "memory");
}
__device__ __forceinline__ void bar_lds(){
  asm volatile("s_waitcnt lgkmcnt(0)" ::: "memory");
  __builtin_amdgcn_s_barrier();
  asm volatile("" ::: "memory");
}
__device__ __forceinline__ void lgkm0(){
  asm volatile("s_waitcnt lgkmcnt(0)" ::: "memory");
}

__launch_bounds__(512, 2)
__global__ void mega(const uint8_t* __restrict__ ws, const float* __restrict__ w2,
                     const float* __restrict__ b1, const float* __restrict__ pw,
                     const float* __restrict__ b2,
                     const float* __restrict__ init_flow, const float* __restrict__ flow_fix,
                     float* __restrict__ out){
  __shared__ uint8_t smem[SMEM_TOTAL];
  const int tid = threadIdx.x;
  const int l   = tid & 63;
  const int w   = tid >> 6;
  // T1: XCD-aware bijective swizzle (896 = 8 * 112)
  const int blk0 = blockIdx.x;
  const int blk  = (blk0 & 7)*112 + (blk0 >> 3);
  const int b   = blk / 448;
  const int p0  = (blk % 448) * 256;

  // --- per-lane staging precompute (inverse-swizzled source addressing) ---
  uint32_t aoff[4], foff72[4], foff73[4], boff[4], bfl[4];
  #pragma unroll
  for(int q = 0; q < 4; q++){
    uint32_t P = (uint32_t)(q*8192 + tid*16);
    uint32_t L = P ^ (((P >> 7) & 7u) << 4);
    int m  = (int)(L >> 7);           // 0..255 pixel row
    int cb = (int)((L >> 4) & 7u);    // ci-block within row
    int p  = p0 + m;
    int y  = p / W_, x = p - y*W_;
    int pixoff = (y + 1)*WP_ + (x + 1);
    aoff[q] = (uint32_t)cb*XPAD_CB_STRIDE32 + (uint32_t)(b*(PPLANE*16)) + (uint32_t)(pixoff*16);
    int dy = cb/3, dx = cb - dy*3;
    foff72[q] = (uint32_t)((b*PPLANE + pixoff + (dy-1)*WP_ + (dx-1))*16);
    foff73[q] = (cb == 0) ? (uint32_t)((b*PPLANE + pixoff + WP_ + 1)*16) : 0u;
  }
  #pragma unroll
  for(int r = 0; r < 4; r++){
    uint32_t P = (uint32_t)(r*8192 + tid*16);
    uint32_t L = P ^ (((P >> 7) & 7u) << 4);
    uint32_t co = L >> 7, cib = L & 127u;
    boff[r] = co*9216u + cib;
    bfl[r]  = co*256u + cib;
  }

  const uint8_t* xpad = ws + XPAD_OFF;
  const uint8_t* fpad = ws + FPAD_OFF;
  const uint8_t* wt   = ws + WT_OFF;
  const uint8_t* wtf  = ws + WTF_OFF;

  // fragment-read per-lane constants
  const int wave_m = w >> 2, wave_n = w & 3;
  const uint32_t koff = ((uint32_t)(l >> 4))*16u;
  const uint32_t sw   = ((uint32_t)(l & 7)) << 4;
  const uint32_t rowA = ((uint32_t)(wave_m*128 + (l & 15)))*128u;
  const uint32_t rowB = ((uint32_t)(wave_n*64  + (l & 15)))*128u;

  const f32x4 zero4 = {0.f, 0.f, 0.f, 0.f};
  f32x4 acc[8][4];
  #pragma unroll
  for(int i = 0; i < 8; i++)
    #pragma unroll
    for(int j = 0; j < 4; j++) acc[i][j] = zero4;

  // staging pieces: A02 = A-chunks {0,2} (logical rows 0-63,128-191 = ph0 rows),
  // A13 = A-chunks {1,3} (rows 64-127,192-255 = ph2 rows), B = all 4 chunks.
  auto STAGE_A02 = [&](int tn, int nb){
    uint8_t* la = smem + nb*TILEBUF + w*1024;
    if(tn < 72){
      int s = tn >> 3, kk = tn & 7;
      int dy = s/3, dx = s - dy*3;
      uint32_t stepA = (uint32_t)(kk*8)*XPAD_CB_STRIDE32 + (uint32_t)(((dy-1)*WP_ + (dx-1))*16);
      gload16(xpad + (aoff[0] + stepA), la);
      gload16(xpad + (aoff[2] + stepA), la + 2*8192);
    } else if(tn == 72){
      gload16(fpad + foff72[0], la);
      gload16(fpad + foff72[2], la + 2*8192);
    } else {
      gload16(fpad + foff73[0], la);
      gload16(fpad + foff73[2], la + 2*8192);
    }
  };
  auto STAGE_A13 = [&](int tn, int nb){
    uint8_t* la = smem + nb*TILEBUF + w*1024;
    if(tn < 72){
      int s = tn >> 3, kk = tn & 7;
      int dy = s/3, dx = s - dy*3;
      uint32_t stepA = (uint32_t)(kk*8)*XPAD_CB_STRIDE32 + (uint32_t)(((dy-1)*WP_ + (dx-1))*16);
      gload16(xpad + (aoff[1] + stepA), la + 1*8192);
      gload16(xpad + (aoff[3] + stepA), la + 3*8192);
    } else if(tn == 72){
      gload16(fpad + foff72[1], la + 1*8192);
      gload16(fpad + foff72[3], la + 3*8192);
    } else {
      gload16(fpad + foff73[1], la + 1*8192);
      gload16(fpad + foff73[3], la + 3*8192);
    }
  };
  auto STAGE_B = [&](int tn, int nb){
    uint8_t* lb = smem + nb*TILEBUF + 32768 + w*1024;
    if(tn < 72){
      int s = tn >> 3, kk = tn & 7;
      uint32_t stepB = (uint32_t)(s*1024 + kk*128);
      #pragma unroll
      for(int r = 0; r < 4; r++) gload16(wt + (boff[r] + stepB), lb + r*8192);
    } else if(tn == 72){
      #pragma unroll
      for(int r = 0; r < 4; r++) gload16(wtf + bfl[r], lb + r*8192);
    } else {
      #pragma unroll
      for(int r = 0; r < 4; r++) gload16(wtf + (bfl[r] + 128u), lb + r*8192);
    }
  };

  // prologue: issue tile 0 (A02, B, A13); wait A02+B (leave A13 in flight)
  STAGE_A02(0, 0);
  STAGE_B(0, 0);
  STAGE_A13(0, 0);
  asm volatile("s_waitcnt vmcnt(2)" ::: "memory");
  bar();

  for(int t = 0; t < 74; t++){
    const uint8_t* A  = smem + (t & 1)*TILEBUF;
    const uint8_t* Bp = A + 32768;
    const int nb = (t & 1) ^ 1;
    const int tn = t + 1;
    bf16x8 av[4], bv0[4], bv1[4];

    // ---- phase 0: rows 0-63 (per wave_m), kc=0 ----
    #pragma unroll
    for(int mi = 0; mi < 4; mi++)
      av[mi] = *(const bf16x8*)(A + ((rowA + (uint32_t)(mi*2048) + koff) ^ sw));
    #pragma unroll
    for(int ni = 0; ni < 4; ni++)
      bv0[ni] = *(const bf16x8*)(Bp + ((rowB + (uint32_t)(ni*2048) + koff) ^ sw));
    if(tn < 74){ STAGE_A02(tn, nb); STAGE_B(tn, nb); }
    bar();
    lgkm0();
    __builtin_amdgcn_s_setprio(1);
    #pragma unroll
    for(int ni = 0; ni < 4; ni++)
      #pragma unroll
      for(int mi = 0; mi < 4; mi++)
        acc[mi][ni] = __builtin_amdgcn_mfma_f32_16x16x32_bf16(av[mi], bv0[ni], acc[mi][ni], 0, 0, 0);
    __builtin_amdgcn_s_setprio(0);
    bar();

    // ---- phase 1: rows 0-63, kc=1 ----
    #pragma unroll
    for(int mi = 0; mi < 4; mi++)
      av[mi] = *(const bf16x8*)(A + ((rowA + (uint32_t)(mi*2048) + 64u + koff) ^ sw));
    #pragma unroll
    for(int ni = 0; ni < 4; ni++)
      bv1[ni] = *(const bf16x8*)(Bp + ((rowB + (uint32_t)(ni*2048) + 64u + koff) ^ sw));
    bar();
    lgkm0();
    __builtin_amdgcn_s_setprio(1);
    #pragma unroll
    for(int ni = 0; ni < 4; ni++)
      #pragma unroll
      for(int mi = 0; mi < 4; mi++)
        acc[mi][ni] = __builtin_amdgcn_mfma_f32_16x16x32_bf16(av[mi], bv1[ni], acc[mi][ni], 0, 0, 0);
    __builtin_amdgcn_s_setprio(0);
    if(t < 73) asm volatile("s_waitcnt vmcnt(6)" ::: "memory");  // retire A13(t)
    else       asm volatile("s_waitcnt vmcnt(0)" ::: "memory");
    bar();

    // ---- phase 2: rows 64-127, kc=0 (bv0 in regs) ----
    #pragma unroll
    for(int mi = 0; mi < 4; mi++)
      av[mi] = *(const bf16x8*)(A + ((rowA + (uint32_t)((mi+4)*2048) + koff) ^ sw));
    if(tn < 74) STAGE_A13(tn, nb);
    bar();
    lgkm0();
    __builtin_amdgcn_s_setprio(1);
    #pragma unroll
    for(int ni = 0; ni < 4; ni++)
      #pragma unroll
      for(int mi = 0; mi < 4; mi++)
        acc[mi+4][ni] = __builtin_amdgcn_mfma_f32_16x16x32_bf16(av[mi], bv0[ni], acc[mi+4][ni], 0, 0, 0);
    __builtin_amdgcn_s_setprio(0);
    bar();

    // ---- phase 3: rows 64-127, kc=1 (bv1 in regs) ----
    #pragma unroll
    for(int mi = 0; mi < 4; mi++)
      av[mi] = *(const bf16x8*)(A + ((rowA + (uint32_t)((mi+4)*2048) + 64u + koff) ^ sw));
    bar();
    lgkm0();
    __builtin_amdgcn_s_setprio(1);
    #pragma unroll
    for(int ni = 0; ni < 4; ni++)
      #pragma unroll
      for(int mi = 0; mi < 4; mi++)
        acc[mi+4][ni] = __builtin_amdgcn_mfma_f32_16x16x32_bf16(av[mi], bv1[ni], acc[mi+4][ni], 0, 0, 0);
    __builtin_amdgcn_s_setprio(0);
    if(t < 73) asm volatile("s_waitcnt vmcnt(2)" ::: "memory");  // retire A02+B(t+1)
    else       asm volatile("s_waitcnt vmcnt(0)" ::: "memory");
    bar();
  }

  // --- stage W2 (fp32 -> bf16) into LDS, rows of 512B, XOR-swizzled ---
  for(int e = tid; e < 48*256; e += 512){
    int row = e >> 8, k = e & 255;
    float f = (row < 36) ? w2[row*256 + k] : 0.f;
    uint32_t phys = ((uint32_t)(row*512 + k*2)) ^ (((uint32_t)(row & 7)) << 4);
    *(ushort_t*)(smem + W2_OFF + phys) = bf16r(f);
  }

  // --- epilogue: two passes of 128 pixels each ---
  #pragma unroll
  for(int pass = 0; pass < 2; pass++){
    if(pass) bar();   // pass-0 softmax/merge done before overwriting x-half & mask
    if(wave_m == pass){
      #pragma unroll
      for(int ni = 0; ni < 4; ni++){
        int co = wave_n*64 + ni*16 + (l & 15);
        float bb = b1[co];
        float pp = pw[co];
        #pragma unroll
        for(int mi = 0; mi < 8; mi++){
          #pragma unroll
          for(int j = 0; j < 4; j++){
            float v = acc[mi][ni][j] + bb;
            v = (v < 0.f) ? v*pp : v;
            int px = mi*16 + ((l >> 4) << 2) + j;     // 0..127 within the pass
            uint32_t phys = ((uint32_t)(px*512 + co*2)) ^ (((uint32_t)(px & 7)) << 4);
            *(ushort_t*)(smem + phys) = bf16r(v);
          }
        }
      }
    }
    bar_lds();   // x-half (and W2 on pass 0) visible to all

    // mask GEMM: wave w -> pixel rows [16w, 16w+16), N=48 (36 valid), K=256
    f32x4 acc2[3];
    #pragma unroll
    for(int ni = 0; ni < 3; ni++) acc2[ni] = zero4;
    {
      const uint32_t rowX = ((uint32_t)(16*w + (l & 15)))*512u;
      #pragma unroll
      for(int kk = 0; kk < 8; kk++){
        bf16x8 av = *(const bf16x8*)(smem + ((rowX + (uint32_t)(kk*64) + koff) ^ sw));
        #pragma unroll
        for(int ni = 0; ni < 3; ni++){
          uint32_t rowW = ((uint32_t)(ni*16 + (l & 15)))*512u;
          bf16x8 bv = *(const bf16x8*)(smem + W2_OFF + ((rowW + (uint32_t)(kk*64) + koff) ^ sw));
          acc2[ni] = __builtin_amdgcn_mfma_f32_16x16x32_bf16(av, bv, acc2[ni], 0, 0, 0);
        }
      }
    }
    {
      float* ml = (float*)(smem + MASK_OFF);
      #pragma unroll
      for(int ni = 0; ni < 3; ni++){
        int co2 = ni*16 + (l & 15);
        float bb2 = b2[co2 < 36 ? co2 : 35];
        #pragma unroll
        for(int j = 0; j < 4; j++){
          int px = 16*w + ((l >> 4) << 2) + j;
          ml[px*48 + co2] = acc2[ni][j] + bb2;
        }
      }
    }
    bar_lds();

    // softmax(2x18) + unfold-merge, 4 threads per pixel (128 px per pass)
    {
      int px = tid >> 2;
      int hh = (tid >> 1) & 1;
      int c  = tid & 1;
      const float* ml = (const float*)(smem + MASK_OFF) + px*48 + hh*18;
      float mx = ml[0];
      #pragma unroll
      for(int k = 1; k < 18; k++) mx = fmaxf(mx, ml[k]);
      float e[18]; float sum = 0.f;
      #pragma unroll
      for(int k = 0; k < 18; k++){ e[k] = __expf(ml[k] - mx); sum += e[k]; }
      float inv = 1.f / sum;
      int p = p0 + pass*128 + px;
      int y = p / W_, x = p - y*W_;
      const float* fi = init_flow + (size_t)(b*4 + 2*hh + c)*NPIX;
      const float* ff = flow_fix  + (size_t)(b*4 + 2*hh + c)*NPIX;
      float o = 0.f;
      #pragma unroll
      for(int s = 0; s < 9; s++){
        int yy = y + (s/3) - 1, xx = x + (s%3) - 1;
        if(yy >= 0 && yy < H_ && xx >= 0 && xx < W_){
          int idx = yy*W_ + xx;
          o += e[s]*fi[idx] + e[9+s]*ff[idx];
        }
      }
      out[(size_t)((b + 2*hh)*2 + c)*NPIX + y*W_ + x] = o * inv;
    }
  }
}

// ---------------- launcher ----------------
extern "C" void kernel_launch(void* const* d_in, const int* in_sizes, int n_in,
                              void* d_out, int out_size, void* d_ws, size_t ws_size,
                              hipStream_t stream) {
  const float* feature   = (const float*)d_in[0];
  const float* init_flow = (const float*)d_in[1];
  const float* flow_fix  = (const float*)d_in[2];
  const float* w1        = (const float*)d_in[3];
  const float* b1        = (const float*)d_in[4];
  const float* prelu_w   = (const float*)d_in[5];
  const float* w2        = (const float*)d_in[6];
  const float* b2        = (const float*)d_in[7];
  float* out = (float*)d_out;
  uint8_t* ws = (uint8_t*)d_ws;

  if(ws_size < WS_NEEDED) return;  // insufficient workspace -> fail visibly

  prep_x<<<64*2*HP_, 256, 0, stream>>>(feature, ws);
  prep_f<<<2*HP_,    256, 0, stream>>>(init_flow, flow_fix, ws);
  prep_w<<<4736,     256, 0, stream>>>(w1, ws);
  mega<<<896, 512, 0, stream>>>(ws, w2, b1, prelu_w, b2, init_flow, flow_fix, out);
}